// Round 10
// baseline (358.012 us; speedup 1.0000x reference)
//
#include <hip/hip_runtime.h>
#include <math.h>

// GATNet forward, MI355X.  R5 (resubmit; prior round infra-failed):
// fuse aggregate-L0 + transform-L1 (x1 never touches HBM); T0 MFMA transform
// unchanged (R4-verified bit-identical).
//
// Pipeline: wfrag_init | T0: emb->h0,es0,ed0 | FUSED: gather(h0)->x1(LDS)->
// MFMA->h1,es1,ed1 | A1: final aggregate over B=4096 dsts -> out.
//
// Evidence log: R3 bf16-h gather FETCH 876->419MB; R4 MFMA transform correct
// (absmax bit-identical 1.22e-4); transforms ~97us each (unexplained, no
// counters yet - fusion makes T0 enter top-5 next round).
//
// Workspace: h0[2][N][128]bf16 | h1[same] | es0,ed0,es1,ed1[2][N][2]f32 |
//            wfrag[2][16384]bf16   (~106 MB)

#define N_NODES 100000
#define DIM     128
#define DH      64
#define DEG     16
#define BATCH   4096

typedef unsigned int   uint32;
typedef unsigned short u16;

typedef __attribute__((ext_vector_type(8))) short bf16x8;   // 8 bf16 = 4 VGPR
typedef __attribute__((ext_vector_type(4))) float f32x4;

static __device__ __forceinline__ u16 bf16rne(float a) {
    uint32 ua = __float_as_uint(a);
    ua = (ua + 0x7FFFu + ((ua >> 16) & 1u)) >> 16;
    return (u16)ua;
}
static __device__ __forceinline__ uint32 bf2pack(float a, float b) {
    uint32 ua = __float_as_uint(a), ub = __float_as_uint(b);
    ua = (ua + 0x7FFFu + ((ua >> 16) & 1u)) >> 16;
    ub = (ub + 0x7FFFu + ((ub >> 16) & 1u)) >> 16;
    return (ub << 16) | (ua & 0xFFFFu);
}

// ---------------------------------------------------------------------------
// W fragments: wfrag[l][ks][nt][lane][j] = bf16(B[ks*32+(lane>>4)*8+j][nt*16+(lane&15)])
// where B[d][c] = Ws[l][c>>6][d][c&63]
// ---------------------------------------------------------------------------
__global__ void wfrag_init(const float* __restrict__ Ws, u16* __restrict__ wfrag) {
    const int l = blockIdx.x;
    for (int i = threadIdx.x; i < 16384; i += 256) {
        const int j = i & 7, lane = (i >> 3) & 63, nt = (i >> 9) & 7, ks = i >> 12;
        const int d = ks * 32 + (lane >> 4) * 8 + j;
        const int c = nt * 16 + (lane & 15);
        const float v = Ws[(size_t)(((l * 2 + (c >> 6)) * DIM) + d) * DH + (c & 63)];
        wfrag[l * 16384 + i] = bf16rne(v);
    }
}

// ---------------------------------------------------------------------------
// MFMA epilogue shared by T0 and the fused kernel: from xsh[64][136] (bf16
// x-tile) compute h (bf16), es, ed for rows row0..row0+63 of graph g.
// C layout (R4-verified): col = lane&15, row = (lane>>4)*4 + reg.
// ---------------------------------------------------------------------------
static __device__ __forceinline__ void mfma_tile_body(
    u16 (*xsh)[136], int t, int g, size_t row0,
    const u16* __restrict__ wfrag, const float* __restrict__ a_src,
    const float* __restrict__ a_dst, u16* __restrict__ hb,
    float* __restrict__ es, float* __restrict__ ed)
{
    const int w = t >> 6, l = t & 63;
    const int wrow = w * 16;
    const int cl = l & 15, kg = l >> 4;

    f32x4 acc[8];
    #pragma unroll
    for (int nt = 0; nt < 8; ++nt) acc[nt] = (f32x4){0.f, 0.f, 0.f, 0.f};

    #pragma unroll
    for (int ks = 0; ks < 4; ++ks) {
        const bf16x8 a = *(const bf16x8*)&xsh[wrow + cl][ks * 32 + kg * 8];
        const u16* wp = wfrag + ks * 4096 + l * 8;
        #pragma unroll
        for (int nt = 0; nt < 8; ++nt) {
            const bf16x8 b = *(const bf16x8*)(wp + nt * 512);
            acc[nt] = __builtin_amdgcn_mfma_f32_16x16x32_bf16(a, b, acc[nt], 0, 0, 0);
        }
    }

    // es/ed: per-lane partials over owned cols, reduce across 16-lane row group
    float av0[4], av1[4], dv0[4], dv1[4];
    #pragma unroll
    for (int nt = 0; nt < 4; ++nt) {
        av0[nt] = a_src[nt * 16 + cl];
        av1[nt] = a_src[DH + nt * 16 + cl];
        dv0[nt] = a_dst[nt * 16 + cl];
        dv1[nt] = a_dst[DH + nt * 16 + cl];
    }
    float pe0[4] = {0,0,0,0}, pe1[4] = {0,0,0,0};
    float pd0[4] = {0,0,0,0}, pd1[4] = {0,0,0,0};
    #pragma unroll
    for (int r = 0; r < 4; ++r)
        #pragma unroll
        for (int nt = 0; nt < 4; ++nt) {
            pe0[r] = fmaf(acc[nt][r],     av0[nt], pe0[r]);
            pd0[r] = fmaf(acc[nt][r],     dv0[nt], pd0[r]);
            pe1[r] = fmaf(acc[nt + 4][r], av1[nt], pe1[r]);
            pd1[r] = fmaf(acc[nt + 4][r], dv1[nt], pd1[r]);
        }
    #pragma unroll
    for (int msk = 1; msk < 16; msk <<= 1)
        #pragma unroll
        for (int r = 0; r < 4; ++r) {
            pe0[r] += __shfl_xor(pe0[r], msk, 64);
            pe1[r] += __shfl_xor(pe1[r], msk, 64);
            pd0[r] += __shfl_xor(pd0[r], msk, 64);
            pd1[r] += __shfl_xor(pd1[r], msk, 64);
        }
    if (cl == 0) {
        #pragma unroll
        for (int r = 0; r < 4; ++r) {
            const size_t gr = row0 + wrow + kg * 4 + r;
            if (gr < N_NODES) {
                const size_t o = ((size_t)g * N_NODES + gr) * 2;
                es[o] = pe0[r]; es[o + 1] = pe1[r];
                ed[o] = pd0[r]; ed[o + 1] = pd1[r];
            }
        }
    }

    // C -> LDS (bf16) -> coalesced global store
    __syncthreads();
    #pragma unroll
    for (int nt = 0; nt < 8; ++nt)
        #pragma unroll
        for (int r = 0; r < 4; ++r)
            xsh[wrow + kg * 4 + r][nt * 16 + cl] = bf16rne(acc[nt][r]);
    __syncthreads();
    #pragma unroll
    for (int i = 0; i < 4; ++i) {
        const int c = i * 256 + t;
        const int r = c >> 4, col = (c & 15) * 8;
        const size_t gr = row0 + r;
        if (gr < N_NODES)
            *(uint4*)(hb + ((size_t)g * N_NODES + gr) * DIM + col) = *(const uint4*)&xsh[r][col];
    }
}

// ---------------------------------------------------------------------------
// T0: fp32 emb -> LDS bf16 -> MFMA -> h0, es0, ed0.
// ---------------------------------------------------------------------------
__global__ __launch_bounds__(256) void gat_transform_mfma(
    const float* __restrict__ xa, const float* __restrict__ xb,
    const u16* __restrict__ wfrag,
    const float* __restrict__ a_src, const float* __restrict__ a_dst,
    u16* __restrict__ hb, float* __restrict__ es, float* __restrict__ ed)
{
    __shared__ u16 xsh[64][136];
    const int g = blockIdx.y;
    const size_t row0 = (size_t)blockIdx.x * 64;
    const int t = threadIdx.x;

    const float* __restrict__ x = (const float*)(g ? xb : xa);
    #pragma unroll
    for (int i = 0; i < 8; ++i) {
        const int c = i * 256 + t;
        const int r = c >> 5, col = (c & 31) * 4;
        const size_t gr = row0 + r;
        float4 v = make_float4(0.f, 0.f, 0.f, 0.f);
        if (gr < N_NODES) v = *(const float4*)(x + gr * DIM + col);
        uint2 pk; pk.x = bf2pack(v.x, v.y); pk.y = bf2pack(v.z, v.w);
        *(uint2*)&xsh[r][col] = pk;
    }
    __syncthreads();
    mfma_tile_body(xsh, t, g, row0, wfrag, a_src, a_dst, hb, es, ed);
}

// ---------------------------------------------------------------------------
// FUSED: aggregate L0 for 64 dsts (gather h0, softmax) -> x1 tile in LDS
// (bf16, same bits as R4's x1b round-trip) -> MFMA -> h1, es1, ed1.
// Wave w aggregates dsts w*16..w*16+15 (1 dst per loop iter, lane = dim pair).
// ---------------------------------------------------------------------------
__global__ __launch_bounds__(256) void gat_fused_agg_transform(
    const int* __restrict__ edges_a, const int* __restrict__ edges_b,
    const u16* __restrict__ h0, const float* __restrict__ es0,
    const float* __restrict__ ed0,
    const u16* __restrict__ wfrag,
    const float* __restrict__ a_src, const float* __restrict__ a_dst,
    u16* __restrict__ h1, float* __restrict__ es1, float* __restrict__ ed1)
{
    __shared__ u16 xsh[64][136];
    const int g = blockIdx.y;
    const int t = threadIdx.x;
    const int w = t >> 6, lane = t & 63;
    const int head = lane >> 5;
    const size_t dst0 = (size_t)blockIdx.x * 64;

    const int* __restrict__ edges = g ? edges_b : edges_a;
    const u16* __restrict__ hg    = h0  + (size_t)g * N_NODES * DIM;
    const float* __restrict__ esg = es0 + (size_t)g * N_NODES * 2;
    const float* __restrict__ edg = ed0 + (size_t)g * N_NODES * 2;

    for (int i = 0; i < 16; ++i) {
        const int r = w * 16 + i;
        const size_t n = dst0 + r;
        uint32 pk = 0u;
        if (n < N_NODES) {
            int s[17];
            const int4* ep = (const int4*)(edges + n * DEG);
            int4 q0 = ep[0], q1 = ep[1], q2 = ep[2], q3 = ep[3];
            s[0]=q0.x;  s[1]=q0.y;  s[2]=q0.z;  s[3]=q0.w;
            s[4]=q1.x;  s[5]=q1.y;  s[6]=q1.z;  s[7]=q1.w;
            s[8]=q2.x;  s[9]=q2.y;  s[10]=q2.z; s[11]=q2.w;
            s[12]=q3.x; s[13]=q3.y; s[14]=q3.z; s[15]=q3.w;
            s[16]=(int)n;

            const float edn = edg[n * 2 + head];
            float wgt[17];
            float m = -1e30f;
            #pragma unroll
            for (int j = 0; j < 17; ++j) {
                float v = esg[s[j] * 2 + head] + edn;
                v = (v >= 0.f) ? v : 0.2f * v;      // leaky_relu
                wgt[j] = v;
                m = fmaxf(m, v);
            }
            float denom = 0.f;
            #pragma unroll
            for (int j = 0; j < 17; ++j) { wgt[j] = __expf(wgt[j] - m); denom += wgt[j]; }
            const float inv = 1.f / (denom + 1e-16f);

            float2 acc = make_float2(0.f, 0.f);
            #pragma unroll
            for (int j = 0; j < 17; ++j) {
                const uint32 u = *(const uint32*)(hg + (size_t)s[j] * DIM + lane * 2);
                acc.x = fmaf(wgt[j], __uint_as_float(u << 16), acc.x);
                acc.y = fmaf(wgt[j], __uint_as_float(u & 0xFFFF0000u), acc.y);
            }
            acc.x *= inv; acc.y *= inv;
            acc.x = (acc.x > 0.f) ? acc.x : (__expf(acc.x) - 1.f);   // elu
            acc.y = (acc.y > 0.f) ? acc.y : (__expf(acc.y) - 1.f);
            pk = bf2pack(acc.x, acc.y);
        }
        *(uint32*)&xsh[r][lane * 2] = pk;   // 64 lanes x 4B = full 256B row
    }
    __syncthreads();
    mfma_tile_body(xsh, t, g, dst0, wfrag, a_src, a_dst, h1, es1, ed1);
}

// ---------------------------------------------------------------------------
// Final aggregate over B indexed dsts -> d_out fp32.
// ---------------------------------------------------------------------------
__global__ __launch_bounds__(256) void gat_aggregate_final(
    const int* __restrict__ edges_a, const int* __restrict__ edges_b,
    const u16* __restrict__ hb, const float* __restrict__ es,
    const float* __restrict__ ed,
    const int* __restrict__ idx_a, const int* __restrict__ idx_b,
    float* __restrict__ out)
{
    const int g   = blockIdx.y;
    const int wid = blockIdx.x * 4 + (threadIdx.x >> 6);
    if (wid >= BATCH) return;
    const int lane = threadIdx.x & 63;
    const int head = lane >> 5;

    const int n = g ? idx_b[wid] : idx_a[wid];
    const int* __restrict__ edges = g ? edges_b : edges_a;
    const u16* __restrict__ hg   = hb + (size_t)g * N_NODES * DIM;
    const float* __restrict__ esg = es + (size_t)g * N_NODES * 2;

    const float edn = ed[((size_t)g * N_NODES + n) * 2 + head];

    int s[17];
    const int4* ep = (const int4*)(edges + (size_t)n * DEG);
    int4 q0 = ep[0], q1 = ep[1], q2 = ep[2], q3 = ep[3];
    s[0]=q0.x;  s[1]=q0.y;  s[2]=q0.z;  s[3]=q0.w;
    s[4]=q1.x;  s[5]=q1.y;  s[6]=q1.z;  s[7]=q1.w;
    s[8]=q2.x;  s[9]=q2.y;  s[10]=q2.z; s[11]=q2.w;
    s[12]=q3.x; s[13]=q3.y; s[14]=q3.z; s[15]=q3.w;
    s[16]=n;

    float wgt[17];
    float m = -1e30f;
    #pragma unroll
    for (int j = 0; j < 17; ++j) {
        float v = esg[s[j] * 2 + head] + edn;
        v = (v >= 0.f) ? v : 0.2f * v;
        wgt[j] = v;
        m = fmaxf(m, v);
    }
    float denom = 0.f;
    #pragma unroll
    for (int j = 0; j < 17; ++j) { wgt[j] = __expf(wgt[j] - m); denom += wgt[j]; }
    const float inv = 1.f / (denom + 1e-16f);

    float2 acc = make_float2(0.f, 0.f);
    #pragma unroll
    for (int j = 0; j < 17; ++j) {
        const uint32 u = *(const uint32*)(hg + (size_t)s[j] * DIM + lane * 2);
        acc.x = fmaf(wgt[j], __uint_as_float(u << 16), acc.x);
        acc.y = fmaf(wgt[j], __uint_as_float(u & 0xFFFF0000u), acc.y);
    }
    acc.x *= inv; acc.y *= inv;

    float* o = out + ((size_t)g * BATCH + wid) * DIM + lane * 2;
    *(float2*)o = acc;
}

extern "C" void kernel_launch(void* const* d_in, const int* in_sizes, int n_in,
                              void* d_out, int out_size, void* d_ws, size_t ws_size,
                              hipStream_t stream)
{
    const float* emb_sr = (const float*)d_in[0];
    const float* emb_tg = (const float*)d_in[1];
    const float* Ws     = (const float*)d_in[2];   // [2][2][128][64]
    const float* a_src  = (const float*)d_in[3];   // [2][2][64]
    const float* a_dst  = (const float*)d_in[4];
    const int*   edg_sr = (const int*)d_in[5];
    const int*   edg_tg = (const int*)d_in[6];
    const int*   sr_idx = (const int*)d_in[7];
    const int*   tg_idx = (const int*)d_in[8];

    // workspace layout
    u16*   h0    = (u16*)d_ws;                                  // 2*N*128 bf16
    u16*   h1    = h0 + (size_t)2 * N_NODES * DIM;              // 2*N*128 bf16
    float* es0   = (float*)(h1 + (size_t)2 * N_NODES * DIM);    // 2*N*2
    float* ed0   = es0 + (size_t)2 * N_NODES * 2;
    float* es1   = ed0 + (size_t)2 * N_NODES * 2;
    float* ed1   = es1 + (size_t)2 * N_NODES * 2;
    u16*   wfrag = (u16*)(ed1 + (size_t)2 * N_NODES * 2);       // 2*16384

    const dim3 tgrd((N_NODES + 63) / 64, 2);

    wfrag_init<<<2, 256, 0, stream>>>(Ws, wfrag);

    // layer 0 transform
    gat_transform_mfma<<<tgrd, 256, 0, stream>>>(
        emb_sr, emb_tg, wfrag, a_src, a_dst, h0, es0, ed0);

    // fused: aggregate L0 + transform L1
    gat_fused_agg_transform<<<tgrd, 256, 0, stream>>>(
        edg_sr, edg_tg, h0, es0, ed0, wfrag + 16384,
        a_src + 2 * DH, a_dst + 2 * DH, h1, es1, ed1);

    // final aggregate (B indexed dsts)
    gat_aggregate_final<<<dim3(BATCH / 4, 2), 256, 0, stream>>>(
        edg_sr, edg_tg, h1, es1, ed1, sr_idx, tg_idx, (float*)d_out);
}